// Round 10
// baseline (37.169 us; speedup 1.0000x reference)
//
#include <hip/hip_runtime.h>
#include <math.h>

typedef _Float16 h2 __attribute__((ext_vector_type(2)));
typedef _Float16 half8 __attribute__((ext_vector_type(8)));
typedef float f32x16 __attribute__((ext_vector_type(16)));
typedef unsigned int uint32;
typedef unsigned int uint32x4 __attribute__((ext_vector_type(4)));
typedef unsigned int uint32x2 __attribute__((ext_vector_type(2)));

// ---- d_ws layout (float indices) ----
#define WS_MB  0      // merge_b (+pad)
#define WS_B0  4      // base[2][16]
#define WS_Z0  36     // zvec[2][16]
#define WS_W4  68     // lane_W[:, :4] as [h][k] : 64
#define WS_DW  132    // d_W[4]
#define WS_DB  136    // d_b[4]
#define WS_WUH 140    // uint32 WuH[20][8]: f16-pair packed Wu = 160
#define WS_WVH 300    // uint32 WvH[20][8] = 160
#define WS_UB  460    // lane_conv_b[20]
#define WS_PM  480    // int pmask[8]
#define WS_HBP 488    // float[2][16]: hid_b permuted to C-layout rows (0 if row>=20)
#define WS_MWP 520    // float[2][16]: merge_W permuted to C-layout rows (0 if row>=20)
#define WS_HA  552    // uint32[2cf][2step][64][4]: A-fragments of H_cf (f16 pairs) = 1024
// total 1576 floats

__global__ void frap_setup(
    const int* __restrict__ p2m, const int* __restrict__ comp_mask,
    const float* __restrict__ p_emb, const float* __restrict__ d_W, const float* __restrict__ d_b,
    const float* __restrict__ lane_W, const float* __restrict__ lane_b,
    const float* __restrict__ lane_conv_W, const float* __restrict__ lane_conv_b,
    const float* __restrict__ rel_emb, const float* __restrict__ rel_conv_W, const float* __restrict__ rel_conv_b,
    const float* __restrict__ hid_W, const float* __restrict__ hid_b,
    const float* __restrict__ merge_W, const float* __restrict__ merge_b,
    float* __restrict__ ws)
{
    __shared__ float R[40];     // rel factors R[c][o]
    const int t = threadIdx.x;
    const int NTH = 256;

    if (t < 40) {
        int c = t / 20, o = t % 20;
        float s = rel_conv_b[o];
        #pragma unroll
        for (int k = 0; k < 4; ++k)
            s = fmaf(rel_conv_W[o*4+k], fmaxf(rel_emb[c*4+k], 0.f), s);
        R[t] = fmaxf(s, 0.f);
    }
    __syncthreads();

    // A-fragments for v_mfma_f32_32x32x16_f16:
    // A row = lane&31 (= o2), k = (lane>>5)*8 + v, dword j holds (k=2j, k=2j+1).
    uint32* HA = (uint32*)ws + WS_HA;
    for (int e = t; e < 1024; e += NTH) {
        int j    = e & 3;
        int lane = (e >> 2) & 63;
        int step = (e >> 8) & 1;
        int cf   = e >> 9;
        int row  = lane & 31;
        int k0   = step*16 + (lane >> 5)*8 + 2*j;
        float a = 0.f, bq = 0.f;
        if (row < 20) {
            if (k0     < 20) a  = hid_W[row*20 + k0]     * R[cf*20 + k0];
            if (k0 + 1 < 20) bq = hid_W[row*20 + k0 + 1] * R[cf*20 + k0 + 1];
        }
        _Float16 ha_ = (_Float16)a, hb_ = (_Float16)bq;   // RTN
        HA[e] = (uint32)__builtin_bit_cast(unsigned short, ha_)
              | ((uint32)__builtin_bit_cast(unsigned short, hb_) << 16);
    }
    // hid_b / merge_W permuted into C-fragment row order: row=(reg&3)+8*(reg>>2)+4*half
    for (int e = t; e < 32; e += NTH) {
        int half = e >> 4, r = e & 15;
        int row = (r & 3) + 8*(r >> 2) + 4*half;
        ws[WS_HBP + e] = row < 20 ? hid_b[row]   : 0.f;
        ws[WS_MWP + e] = row < 20 ? merge_W[row] : 0.f;
    }
    // WuH/WvH packed f16 pairs over h
    uint32* WuH = (uint32*)ws + WS_WUH;
    uint32* WvH = (uint32*)ws + WS_WVH;
    for (int e = t; e < 160; e += NTH) {
        int jj = e % 8, o = e / 8;
        _Float16 a0 = (_Float16)lane_conv_W[o*32 + 2*jj];
        _Float16 a1 = (_Float16)lane_conv_W[o*32 + 2*jj + 1];
        _Float16 b0 = (_Float16)lane_conv_W[o*32 + 16 + 2*jj];
        _Float16 b1 = (_Float16)lane_conv_W[o*32 + 16 + 2*jj + 1];
        WuH[e] = (uint32)__builtin_bit_cast(unsigned short, a0)
               | ((uint32)__builtin_bit_cast(unsigned short, a1) << 16);
        WvH[e] = (uint32)__builtin_bit_cast(unsigned short, b0)
               | ((uint32)__builtin_bit_cast(unsigned short, b1) << 16);
    }
    for (int i = t; i < 20; i += NTH) ws[WS_UB + i] = lane_conv_b[i];
    if (t == 0) ws[WS_MB] = merge_b[0];
    for (int i = t; i < 32; i += NTH) {
        int c = i >> 4, h = i & 15;
        float s = lane_b[h];
        #pragma unroll
        for (int k = 0; k < 4; ++k) {
            float sg = 1.f/(1.f + __expf(-p_emb[c*4+k]));
            s = fmaf(lane_W[h*8+4+k], sg, s);
        }
        ws[WS_B0 + c*16 + h] = s;              // base_c[h]
        float z = s;
        #pragma unroll
        for (int k = 0; k < 4; ++k) {
            float sg = 1.f/(1.f + __expf(-d_b[k]));
            z = fmaf(lane_W[h*8+k], sg, z);
        }
        ws[WS_Z0 + c*16 + h] = fmaxf(z, 0.f);  // zvec_c[h]
    }
    for (int i = t; i < 64; i += NTH) ws[WS_W4 + i] = lane_W[(i>>2)*8 + (i&3)];
    if (t < 4) { ws[WS_DW + t] = d_W[t]; ws[WS_DB + t] = d_b[t]; }
    int* wi = (int*)ws;
    for (int i = t; i < 8; i += NTH) {
        int mk = 0;
        for (int m = 0; m < 12; ++m) mk |= (p2m[i*12 + m] & 1) << m;
        wi[WS_PM + i] = mk;
    }
}

__device__ __forceinline__ uint32 pkrtz(float a, float b) {
    return __builtin_bit_cast(uint32, __builtin_amdgcn_cvt_pkrtz(a, b));
}

__global__ __launch_bounds__(512, 4) void frap_main(
    const float* __restrict__ states, const int* __restrict__ comp_mask,
    const float* __restrict__ ws, float* __restrict__ out, int B)
{
    // Union LDS: (a) staged states 64x13 f32 (3,328 B) -> (b) t[sample][m][16] f32
    // (stride 20, 61,440 B) -> (c) packed-f16 v (stride 12, 24,576 B).
    __shared__ float smem_f[12*64*20];
    uint32* v_sm = (uint32*)smem_f;

    const int tid  = threadIdx.x;
    const int lane = tid & 63;
    const int p    = __builtin_amdgcn_readfirstlane(tid >> 6);  // wave-uniform phase
    const int b    = blockIdx.x * 64 + lane;
    const int* wi  = (const int*)ws;

    // ---- stage 0: coalesced staging of this block's 64x13 states into LDS ----
    // One float4 pass: 208 lanes x 16B, fully coalesced (vs 13 scatter loads x 8 waves).
    {
        const int nfl = min(832, B*13 - blockIdx.x*832);    // floats available
        const float* gbase = states + (size_t)blockIdx.x * 832;
        if ((nfl & 3) == 0 && (((size_t)gbase) & 15) == 0) {
            const float4* g4 = (const float4*)gbase;
            float4* l4 = (float4*)smem_f;
            if (tid < (nfl >> 2)) l4[tid] = g4[tid];
        } else {
            for (int i = tid; i < nfl; i += 512) smem_f[i] = gbase[i];
        }
    }
    __syncthreads();

    const float* srow = smem_f + lane*13;                   // stride 13: conflict-free
    const int act = b < B ? (int)srow[0] : 0;
    const int cmask = wi[WS_PM + act];                      // lane-varying (per-sample)
    float dm[12];
    #pragma unroll
    for (int m = 0; m < 12; ++m) dm[m] = srow[1+m];
    __syncthreads();    // all dm/act reads done before t overwrites the region

    const int pmask = wi[WS_PM + p];               // scalar

    // ---- stage 1a: thread p computes t[sample][m] for m in {p, p+8 (p<4)} ----
    auto compute_store_t = [&](int m) {
        const bool cbit = (cmask >> m) & 1;
        float e[4];
        #pragma unroll
        for (int k = 0; k < 4; ++k) {
            float xx = fmaf(dm[m], ws[WS_DW+k], ws[WS_DB+k]);
            e[k] = __builtin_amdgcn_rcpf(1.f + __expf(-xx));
        }
        float* dst = &smem_f[(m*64 + lane)*20];
        #pragma unroll
        for (int h4 = 0; h4 < 16; h4 += 4) {
            float4 t4;
            #pragma unroll
            for (int hh = 0; hh < 4; ++hh) {
                int h = h4 + hh;
                float t = cbit ? ws[WS_B0+16+h] : ws[WS_B0+h];
                #pragma unroll
                for (int k = 0; k < 4; ++k)
                    t = fmaf(ws[WS_W4 + h*4 + k], e[k], t);
                (&t4.x)[hh] = fmaxf(t, 0.f);
            }
            *(float4*)(dst + h4) = t4;
        }
    };
    compute_store_t(p);
    if (p < 4) compute_store_t(p + 8);
    __syncthreads();

    // ---- stage 1b: agg = zvec-fold + sum of my pmask movements' t ----
    const int notp = ~pmask & 0xFFF;
    const float cnt1 = (float)__popc(cmask & notp);
    const float cnt0 = (float)__popc(~cmask & notp);

    float agg[16];
    #pragma unroll
    for (int h = 0; h < 16; ++h)
        agg[h] = fmaf(cnt0, ws[WS_Z0+h], cnt1 * ws[WS_Z0+16+h]);

    #pragma unroll
    for (int m = 0; m < 12; ++m) {
        if ((pmask >> m) & 1) {                    // wave-uniform branch
            const float* src = &smem_f[(m*64 + lane)*20];
            #pragma unroll
            for (int h4 = 0; h4 < 16; h4 += 4) {
                float4 t4 = *(const float4*)(src + h4);
                agg[h4]   += t4.x;
                agg[h4+1] += t4.y;
                agg[h4+2] += t4.z;
                agg[h4+3] += t4.w;
            }
        }
    }

    // ---- stage 2: pack agg -> f16; u,v via fdot2 ----
    uint32 aggh[8];
    #pragma unroll
    for (int jj = 0; jj < 8; ++jj) aggh[jj] = pkrtz(agg[2*jj], agg[2*jj+1]);

    const uint32* WuH = (const uint32*)ws + WS_WUH;
    const uint32* WvH = (const uint32*)ws + WS_WVH;
    uint32 upk[10], vpk[10];
    #pragma unroll
    for (int op = 0; op < 10; ++op) {
        float su0 = ws[WS_UB + 2*op], su1 = ws[WS_UB + 2*op + 1];
        float sv0 = 0.f, sv1 = 0.f;
        #pragma unroll
        for (int jj = 0; jj < 8; ++jj) {
            h2 a = __builtin_bit_cast(h2, aggh[jj]);
            su0 = __builtin_amdgcn_fdot2(__builtin_bit_cast(h2, WuH[(2*op)*8 + jj]),   a, su0, false);
            su1 = __builtin_amdgcn_fdot2(__builtin_bit_cast(h2, WuH[(2*op+1)*8 + jj]), a, su1, false);
            sv0 = __builtin_amdgcn_fdot2(__builtin_bit_cast(h2, WvH[(2*op)*8 + jj]),   a, sv0, false);
            sv1 = __builtin_amdgcn_fdot2(__builtin_bit_cast(h2, WvH[(2*op+1)*8 + jj]), a, sv1, false);
        }
        upk[op] = pkrtz(su0, su1);
        vpk[op] = pkrtz(sv0, sv1);
    }
    __syncthreads();   // all t reads done; safe to overwrite LDS with v

    {
        uint32* vdst = &v_sm[(p*64 + lane)*12];
        uint32x4 w0 = {vpk[0], vpk[1], vpk[2], vpk[3]};
        uint32x4 w1 = {vpk[4], vpk[5], vpk[6], vpk[7]};
        uint32x2 w2 = {vpk[8], vpk[9]};
        *(uint32x4*)(vdst)     = w0;
        *(uint32x4*)(vdst + 4) = w1;
        *(uint32x2*)(vdst + 8) = w2;
    }
    __syncthreads();

    // ---- stage 3: MFMA per qi ----
    const uint32* HAp = (const uint32*)ws + WS_HA;
    half8 A00, A10, A01, A11;  // A{step}{cf}
    {
        uint32x4 w0 = *(const uint32x4*)(HAp + (0*64 + lane)*4);
        uint32x4 w1 = *(const uint32x4*)(HAp + (1*64 + lane)*4);
        uint32x4 w2 = *(const uint32x4*)(HAp + (2*64 + lane)*4);
        uint32x4 w3 = *(const uint32x4*)(HAp + (3*64 + lane)*4);
        A00 = __builtin_bit_cast(half8, w0);
        A10 = __builtin_bit_cast(half8, w1);
        A01 = __builtin_bit_cast(half8, w2);
        A11 = __builtin_bit_cast(half8, w3);
    }
    const int halfsel = lane >> 5;
    f32x16 hbacc;
    #pragma unroll
    for (int r = 0; r < 16; ++r) hbacc[r] = ws[WS_HBP + halfsel*16 + r];
    float mwv[12];
    #pragma unroll
    for (int r = 0; r < 12; ++r) mwv[r] = ws[WS_MWP + halfsel*16 + r];

    const int srcT0 = (lane & 31) * 4;         // partner holding sample lane&31
    const int srcT1 = (32 | (lane & 31)) * 4;  // partner holding sample 32|(lane&31)
    const int srcX  = (lane ^ 32) * 4;
    const bool lo = lane < 32;
    const h2 z2 = {(_Float16)0.f, (_Float16)0.f};

    float qA = 0.f, qB = 0.f;
    for (int qi = 0; qi < 7; ++qi) {
        const int j   = qi + (qi >= p ? 1 : 0);            // scalar
        const bool cf = comp_mask[p*7 + qi] != 0;          // scalar
        const uint32* vj = &v_sm[(j*64 + lane)*12];
        uint32x4 va = *(const uint32x4*)vj;
        uint32x4 vb = *(const uint32x4*)(vj + 4);
        uint32x2 vc = *(const uint32x2*)(vj + 8);
        uint32 vjw[10] = {va[0], va[1], va[2], va[3], vb[0], vb[1], vb[2], vb[3], vc[0], vc[1]};
        uint32 ypk[10];
        #pragma unroll
        for (int jj = 0; jj < 10; ++jj) {
            h2 t = __builtin_bit_cast(h2, upk[jj]) + __builtin_bit_cast(h2, vjw[jj]);
            ypk[jj] = __builtin_bit_cast(uint32, __builtin_elementwise_max(t, z2));
        }
        // B-fragments: col=lane&31 (sample in tile), k=(lane>>5)*8+v.
        uint32 f00[4], f10[4];
        #pragma unroll
        for (int j2 = 0; j2 < 4; ++j2) {
            uint32 t0 = (uint32)__builtin_amdgcn_ds_bpermute(srcT0, (int)ypk[4+j2]);
            uint32 t1 = (uint32)__builtin_amdgcn_ds_bpermute(srcT1, (int)ypk[j2]);
            f00[j2] = lo ? ypk[j2] : t0;       // tile0 K-step0
            f10[j2] = lo ? t1 : ypk[4+j2];     // tile1 K-step0
        }
        uint32 t8 = (uint32)__builtin_amdgcn_ds_bpermute(srcT1, (int)ypk[8]);
        uint32 t9 = (uint32)__builtin_amdgcn_ds_bpermute(srcT1, (int)ypk[9]);
        uint32x4 f00v = {f00[0], f00[1], f00[2], f00[3]};
        uint32x4 f10v = {f10[0], f10[1], f10[2], f10[3]};
        uint32x4 f01v = {lo ? ypk[8] : 0u, lo ? ypk[9] : 0u, 0u, 0u};  // tile0 K-step1
        uint32x4 f11v = {lo ? t8 : 0u,     lo ? t9 : 0u,     0u, 0u};  // tile1 K-step1

        half8 A0 = cf ? A01 : A00;
        half8 A1 = cf ? A11 : A10;

        f32x16 c0 = __builtin_amdgcn_mfma_f32_32x32x16_f16(A0, __builtin_bit_cast(half8, f00v), hbacc, 0, 0, 0);
        c0 = __builtin_amdgcn_mfma_f32_32x32x16_f16(A1, __builtin_bit_cast(half8, f01v), c0, 0, 0, 0);
        f32x16 c1 = __builtin_amdgcn_mfma_f32_32x32x16_f16(A0, __builtin_bit_cast(half8, f10v), hbacc, 0, 0, 0);
        c1 = __builtin_amdgcn_mfma_f32_32x32x16_f16(A1, __builtin_bit_cast(half8, f11v), c1, 0, 0, 0);

        #pragma unroll
        for (int r = 0; r < 12; ++r) qA = fmaf(mwv[r], fmaxf(c0[r], 0.f), qA);
        #pragma unroll
        for (int r = 0; r < 12; ++r) qB = fmaf(mwv[r], fmaxf(c1[r], 0.f), qB);
    }

    // combine lane halves
    float sA = __builtin_bit_cast(float, __builtin_amdgcn_ds_bpermute(srcX, __builtin_bit_cast(int, qA)));
    float sB = __builtin_bit_cast(float, __builtin_amdgcn_ds_bpermute(srcX, __builtin_bit_cast(int, qB)));
    float qv = (lo ? qA + sA : qB + sB) + 7.f * ws[WS_MB];
    if (b < B) out[(size_t)b*8 + p] = qv;
}

extern "C" void kernel_launch(void* const* d_in, const int* in_sizes, int n_in,
                              void* d_out, int out_size, void* d_ws, size_t ws_size,
                              hipStream_t stream) {
    const float* states       = (const float*)d_in[0];
    const int*   p2m          = (const int*)  d_in[1];
    const int*   comp_mask    = (const int*)  d_in[3];
    const float* p_emb        = (const float*)d_in[4];
    const float* d_W          = (const float*)d_in[5];
    const float* d_b          = (const float*)d_in[6];
    const float* lane_W       = (const float*)d_in[7];
    const float* lane_b       = (const float*)d_in[8];
    const float* lane_conv_W  = (const float*)d_in[9];
    const float* lane_conv_b  = (const float*)d_in[10];
    const float* rel_emb      = (const float*)d_in[11];
    const float* rel_conv_W   = (const float*)d_in[12];
    const float* rel_conv_b   = (const float*)d_in[13];
    const float* hid_W        = (const float*)d_in[14];
    const float* hid_b        = (const float*)d_in[15];
    const float* merge_W      = (const float*)d_in[16];
    const float* merge_b      = (const float*)d_in[17];
    float* out = (float*)d_out;
    float* ws  = (float*)d_ws;

    frap_setup<<<1, 256, 0, stream>>>(p2m, comp_mask, p_emb, d_W, d_b, lane_W, lane_b,
        lane_conv_W, lane_conv_b, rel_emb, rel_conv_W, rel_conv_b, hid_W, hid_b,
        merge_W, merge_b, ws);

    int B = in_sizes[0] / 13;
    int grid = (B + 63) / 64;
    frap_main<<<grid, 512, 0, stream>>>(states, comp_mask, ws, out, B);
}

// Round 11
// 36.762 us; speedup vs baseline: 1.0111x; 1.0111x over previous
//
#include <hip/hip_runtime.h>
#include <math.h>

typedef _Float16 h2 __attribute__((ext_vector_type(2)));
typedef _Float16 half8 __attribute__((ext_vector_type(8)));
typedef float f32x16 __attribute__((ext_vector_type(16)));
typedef unsigned int uint32;
typedef unsigned int uint32x4 __attribute__((ext_vector_type(4)));
typedef unsigned int uint32x2 __attribute__((ext_vector_type(2)));

// ---- d_ws layout (float indices) ----
#define WS_MB  0      // merge_b (+pad)
#define WS_B0  4      // base[2][16]
#define WS_Z0  36     // zvec[2][16]
#define WS_W4  68     // lane_W[:, :4] as [h][k] : 64
#define WS_DW  132    // d_W[4]
#define WS_DB  136    // d_b[4]
#define WS_WUH 140    // uint32 WuH[20][8]: f16-pair packed Wu = 160
#define WS_WVH 300    // uint32 WvH[20][8] = 160
#define WS_UB  460    // lane_conv_b[20]
#define WS_PM  480    // int pmask[8]
#define WS_HBP 488    // float[2][16]: hid_b permuted to C-layout rows (0 if row>=20)
#define WS_MWP 520    // float[2][16]: merge_W permuted to C-layout rows (0 if row>=20)
#define WS_HA  552    // uint32[2cf][2step][64][4]: A-fragments of H_cf (f16 pairs) = 1024
// total 1576 floats

__global__ void frap_setup(
    const int* __restrict__ p2m, const int* __restrict__ comp_mask,
    const float* __restrict__ p_emb, const float* __restrict__ d_W, const float* __restrict__ d_b,
    const float* __restrict__ lane_W, const float* __restrict__ lane_b,
    const float* __restrict__ lane_conv_W, const float* __restrict__ lane_conv_b,
    const float* __restrict__ rel_emb, const float* __restrict__ rel_conv_W, const float* __restrict__ rel_conv_b,
    const float* __restrict__ hid_W, const float* __restrict__ hid_b,
    const float* __restrict__ merge_W, const float* __restrict__ merge_b,
    float* __restrict__ ws)
{
    __shared__ float R[40];     // rel factors R[c][o]
    const int t = threadIdx.x;
    const int NTH = 256;

    if (t < 40) {
        int c = t / 20, o = t % 20;
        float s = rel_conv_b[o];
        #pragma unroll
        for (int k = 0; k < 4; ++k)
            s = fmaf(rel_conv_W[o*4+k], fmaxf(rel_emb[c*4+k], 0.f), s);
        R[t] = fmaxf(s, 0.f);
    }
    __syncthreads();

    // A-fragments for v_mfma_f32_32x32x16_f16:
    // A row = lane&31 (= o2), k = (lane>>5)*8 + v, dword j holds (k=2j, k=2j+1).
    uint32* HA = (uint32*)ws + WS_HA;
    for (int e = t; e < 1024; e += NTH) {
        int j    = e & 3;
        int lane = (e >> 2) & 63;
        int step = (e >> 8) & 1;
        int cf   = e >> 9;
        int row  = lane & 31;
        int k0   = step*16 + (lane >> 5)*8 + 2*j;
        float a = 0.f, bq = 0.f;
        if (row < 20) {
            if (k0     < 20) a  = hid_W[row*20 + k0]     * R[cf*20 + k0];
            if (k0 + 1 < 20) bq = hid_W[row*20 + k0 + 1] * R[cf*20 + k0 + 1];
        }
        _Float16 ha_ = (_Float16)a, hb_ = (_Float16)bq;   // RTN
        HA[e] = (uint32)__builtin_bit_cast(unsigned short, ha_)
              | ((uint32)__builtin_bit_cast(unsigned short, hb_) << 16);
    }
    // hid_b / merge_W permuted into C-fragment row order: row=(reg&3)+8*(reg>>2)+4*half
    for (int e = t; e < 32; e += NTH) {
        int half = e >> 4, r = e & 15;
        int row = (r & 3) + 8*(r >> 2) + 4*half;
        ws[WS_HBP + e] = row < 20 ? hid_b[row]   : 0.f;
        ws[WS_MWP + e] = row < 20 ? merge_W[row] : 0.f;
    }
    // WuH/WvH packed f16 pairs over h
    uint32* WuH = (uint32*)ws + WS_WUH;
    uint32* WvH = (uint32*)ws + WS_WVH;
    for (int e = t; e < 160; e += NTH) {
        int jj = e % 8, o = e / 8;
        _Float16 a0 = (_Float16)lane_conv_W[o*32 + 2*jj];
        _Float16 a1 = (_Float16)lane_conv_W[o*32 + 2*jj + 1];
        _Float16 b0 = (_Float16)lane_conv_W[o*32 + 16 + 2*jj];
        _Float16 b1 = (_Float16)lane_conv_W[o*32 + 16 + 2*jj + 1];
        WuH[e] = (uint32)__builtin_bit_cast(unsigned short, a0)
               | ((uint32)__builtin_bit_cast(unsigned short, a1) << 16);
        WvH[e] = (uint32)__builtin_bit_cast(unsigned short, b0)
               | ((uint32)__builtin_bit_cast(unsigned short, b1) << 16);
    }
    for (int i = t; i < 20; i += NTH) ws[WS_UB + i] = lane_conv_b[i];
    if (t == 0) ws[WS_MB] = merge_b[0];
    for (int i = t; i < 32; i += NTH) {
        int c = i >> 4, h = i & 15;
        float s = lane_b[h];
        #pragma unroll
        for (int k = 0; k < 4; ++k) {
            float sg = 1.f/(1.f + __expf(-p_emb[c*4+k]));
            s = fmaf(lane_W[h*8+4+k], sg, s);
        }
        ws[WS_B0 + c*16 + h] = s;              // base_c[h]
        float z = s;
        #pragma unroll
        for (int k = 0; k < 4; ++k) {
            float sg = 1.f/(1.f + __expf(-d_b[k]));
            z = fmaf(lane_W[h*8+k], sg, z);
        }
        ws[WS_Z0 + c*16 + h] = fmaxf(z, 0.f);  // zvec_c[h]
    }
    for (int i = t; i < 64; i += NTH) ws[WS_W4 + i] = lane_W[(i>>2)*8 + (i&3)];
    if (t < 4) { ws[WS_DW + t] = d_W[t]; ws[WS_DB + t] = d_b[t]; }
    int* wi = (int*)ws;
    for (int i = t; i < 8; i += NTH) {
        int mk = 0;
        for (int m = 0; m < 12; ++m) mk |= (p2m[i*12 + m] & 1) << m;
        wi[WS_PM + i] = mk;
    }
}

__device__ __forceinline__ uint32 pkrtz(float a, float b) {
    return __builtin_bit_cast(uint32, __builtin_amdgcn_cvt_pkrtz(a, b));
}

// y = max(a + b, 0) on packed f16 pairs (bit-identical to r8/r9 path)
__device__ __forceinline__ uint32 pkmaxadd(uint32 a, uint32 b) {
    const h2 z2 = {(_Float16)0.f, (_Float16)0.f};
    h2 t = __builtin_bit_cast(h2, a) + __builtin_bit_cast(h2, b);
    return __builtin_bit_cast(uint32, __builtin_elementwise_max(t, z2));
}

__global__ __launch_bounds__(512, 4) void frap_main(
    const float* __restrict__ states, const int* __restrict__ comp_mask,
    const float* __restrict__ ws, float* __restrict__ out, int B)
{
    // Union LDS: (a) t[movement][sample][20] f32, 61,440 B
    //            (b) u[512][12] + v[512][12] packed-f16 dwords, 49,152 B
    __shared__ uint32 smem[15360];
    float* smem_f = (float*)smem;
    const int V_OFF = 6144;     // v region base (dwords); u at 0 (max 6141 < 6144)

    const int tid  = threadIdx.x;
    const int lane = tid & 63;
    const int p    = __builtin_amdgcn_readfirstlane(tid >> 6);  // wave-uniform phase
    const int b    = blockIdx.x * 64 + lane;
    const int bc   = b < B ? b : B - 1;
    const int* wi  = (const int*)ws;

    const float* srow = states + (size_t)bc * 13;   // direct loads (r10 staging was null)
    const int cmask = wi[WS_PM + (int)srow[0]];     // lane-varying (per-sample)
    float dm[12];
    #pragma unroll
    for (int m = 0; m < 12; ++m) dm[m] = srow[1+m];

    const int pmask = wi[WS_PM + p];                // scalar

    // ---- stage 1a: thread p computes t[sample][m] for m in {p, p+8 (p<4)} ----
    auto compute_store_t = [&](int m) {
        const bool cbit = (cmask >> m) & 1;
        float e[4];
        #pragma unroll
        for (int k = 0; k < 4; ++k) {
            float xx = fmaf(dm[m], ws[WS_DW+k], ws[WS_DB+k]);
            e[k] = __builtin_amdgcn_rcpf(1.f + __expf(-xx));
        }
        float* dst = &smem_f[(m*64 + lane)*20];
        #pragma unroll
        for (int h4 = 0; h4 < 16; h4 += 4) {
            float4 t4;
            #pragma unroll
            for (int hh = 0; hh < 4; ++hh) {
                int h = h4 + hh;
                float t = cbit ? ws[WS_B0+16+h] : ws[WS_B0+h];
                #pragma unroll
                for (int k = 0; k < 4; ++k)
                    t = fmaf(ws[WS_W4 + h*4 + k], e[k], t);
                (&t4.x)[hh] = fmaxf(t, 0.f);
            }
            *(float4*)(dst + h4) = t4;
        }
    };
    compute_store_t(p);
    if (p < 4) compute_store_t(p + 8);
    __syncthreads();                                // B1: t visible

    // ---- stage 1b: agg = zvec-fold + sum of my pmask movements' t ----
    const int notp = ~pmask & 0xFFF;
    const float cnt1 = (float)__popc(cmask & notp);
    const float cnt0 = (float)__popc(~cmask & notp);

    float agg[16];
    #pragma unroll
    for (int h = 0; h < 16; ++h)
        agg[h] = fmaf(cnt0, ws[WS_Z0+h], cnt1 * ws[WS_Z0+16+h]);

    #pragma unroll
    for (int m = 0; m < 12; ++m) {
        if ((pmask >> m) & 1) {                     // wave-uniform branch
            const float* src = &smem_f[(m*64 + lane)*20];
            #pragma unroll
            for (int h4 = 0; h4 < 16; h4 += 4) {
                float4 t4 = *(const float4*)(src + h4);
                agg[h4]   += t4.x;
                agg[h4+1] += t4.y;
                agg[h4+2] += t4.z;
                agg[h4+3] += t4.w;
            }
        }
    }

    // ---- stage 2: pack agg -> f16; u,v via fdot2 ----
    uint32 aggh[8];
    #pragma unroll
    for (int jj = 0; jj < 8; ++jj) aggh[jj] = pkrtz(agg[2*jj], agg[2*jj+1]);

    const uint32* WuH = (const uint32*)ws + WS_WUH;
    const uint32* WvH = (const uint32*)ws + WS_WVH;
    uint32 upk[10], vpk[10];
    #pragma unroll
    for (int op = 0; op < 10; ++op) {
        float su0 = ws[WS_UB + 2*op], su1 = ws[WS_UB + 2*op + 1];
        float sv0 = 0.f, sv1 = 0.f;
        #pragma unroll
        for (int jj = 0; jj < 8; ++jj) {
            h2 a = __builtin_bit_cast(h2, aggh[jj]);
            su0 = __builtin_amdgcn_fdot2(__builtin_bit_cast(h2, WuH[(2*op)*8 + jj]),   a, su0, false);
            su1 = __builtin_amdgcn_fdot2(__builtin_bit_cast(h2, WuH[(2*op+1)*8 + jj]), a, su1, false);
            sv0 = __builtin_amdgcn_fdot2(__builtin_bit_cast(h2, WvH[(2*op)*8 + jj]),   a, sv0, false);
            sv1 = __builtin_amdgcn_fdot2(__builtin_bit_cast(h2, WvH[(2*op+1)*8 + jj]), a, sv1, false);
        }
        upk[op] = pkrtz(su0, su1);
        vpk[op] = pkrtz(sv0, sv1);
    }
    __syncthreads();                                // B2: all t reads done; region reusable

    {
        uint32* ud = &smem[tid*12];
        uint32x4 a0 = {upk[0], upk[1], upk[2], upk[3]};
        uint32x4 a1 = {upk[4], upk[5], upk[6], upk[7]};
        uint32x2 a2 = {upk[8], upk[9]};
        *(uint32x4*)(ud)     = a0;
        *(uint32x4*)(ud + 4) = a1;
        *(uint32x2*)(ud + 8) = a2;
        uint32* vd = &smem[V_OFF + tid*12];
        uint32x4 b0 = {vpk[0], vpk[1], vpk[2], vpk[3]};
        uint32x4 b1 = {vpk[4], vpk[5], vpk[6], vpk[7]};
        uint32x2 b2 = {vpk[8], vpk[9]};
        *(uint32x4*)(vd)     = b0;
        *(uint32x4*)(vd + 4) = b1;
        *(uint32x2*)(vd + 8) = b2;
    }
    __syncthreads();                                // B3: u/v visible

    // ---- stage 3: MFMA; B-fragments read straight from u/v LDS (no bpermute) ----
    const uint32* HAp = (const uint32*)ws + WS_HA;
    half8 A00, A10, A01, A11;  // A{step}{cf}
    {
        uint32x4 w0 = *(const uint32x4*)(HAp + (0*64 + lane)*4);
        uint32x4 w1 = *(const uint32x4*)(HAp + (1*64 + lane)*4);
        uint32x4 w2 = *(const uint32x4*)(HAp + (2*64 + lane)*4);
        uint32x4 w3 = *(const uint32x4*)(HAp + (3*64 + lane)*4);
        A00 = __builtin_bit_cast(half8, w0);
        A10 = __builtin_bit_cast(half8, w1);
        A01 = __builtin_bit_cast(half8, w2);
        A11 = __builtin_bit_cast(half8, w3);
    }
    const int halfsel = lane >> 5;
    const bool lo = lane < 32;
    f32x16 hbacc;
    #pragma unroll
    for (int r = 0; r < 16; ++r) hbacc[r] = ws[WS_HBP + halfsel*16 + r];
    float mwv[12];
    #pragma unroll
    for (int r = 0; r < 12; ++r) mwv[r] = ws[WS_MWP + halfsel*16 + r];

    // u-fragments: qi-invariant, hoisted. Row for tile t = p*64 + t*32 + (lane&31).
    const int cbase = (tid & ~63) + (lane & 31);    // p*64 + (lane&31)
    const int koff  = halfsel*4;                    // kstep0 dword offset
    uint32x4 u0k0 = *(const uint32x4*)&smem[(cbase     )*12 + koff];
    uint32x4 u1k0 = *(const uint32x4*)&smem[(cbase + 32)*12 + koff];
    uint32x2 u0k1 = *(const uint32x2*)&smem[(cbase     )*12 + 8];
    uint32x2 u1k1 = *(const uint32x2*)&smem[(cbase + 32)*12 + 8];

    const int srcX = (lane ^ 32) * 4;
    float qA = 0.f, qB = 0.f;
    for (int qi = 0; qi < 7; ++qi) {
        const int j   = qi + (qi >= p ? 1 : 0);     // scalar
        const bool cf = comp_mask[p*7 + qi] != 0;   // scalar
        const uint32* vbase = &smem[V_OFF + (j*64 + (lane & 31))*12];
        uint32x4 v0k0 = *(const uint32x4*)&vbase[koff];
        uint32x4 v1k0 = *(const uint32x4*)&vbase[32*12 + koff];
        uint32x2 v0k1 = *(const uint32x2*)&vbase[8];
        uint32x2 v1k1 = *(const uint32x2*)&vbase[32*12 + 8];

        uint32x4 f00v, f10v;
        #pragma unroll
        for (int d = 0; d < 4; ++d) {
            f00v[d] = pkmaxadd(u0k0[d], v0k0[d]);
            f10v[d] = pkmaxadd(u1k0[d], v1k0[d]);
        }
        uint32 y01a = pkmaxadd(u0k1[0], v0k1[0]);
        uint32 y01b = pkmaxadd(u0k1[1], v0k1[1]);
        uint32 y11a = pkmaxadd(u1k1[0], v1k1[0]);
        uint32 y11b = pkmaxadd(u1k1[1], v1k1[1]);
        uint32x4 f01v = {lo ? y01a : 0u, lo ? y01b : 0u, 0u, 0u};  // tile0 kstep1
        uint32x4 f11v = {lo ? y11a : 0u, lo ? y11b : 0u, 0u, 0u};  // tile1 kstep1

        half8 A0 = cf ? A01 : A00;
        half8 A1 = cf ? A11 : A10;

        f32x16 c0 = __builtin_amdgcn_mfma_f32_32x32x16_f16(A0, __builtin_bit_cast(half8, f00v), hbacc, 0, 0, 0);
        c0 = __builtin_amdgcn_mfma_f32_32x32x16_f16(A1, __builtin_bit_cast(half8, f01v), c0, 0, 0, 0);
        f32x16 c1 = __builtin_amdgcn_mfma_f32_32x32x16_f16(A0, __builtin_bit_cast(half8, f10v), hbacc, 0, 0, 0);
        c1 = __builtin_amdgcn_mfma_f32_32x32x16_f16(A1, __builtin_bit_cast(half8, f11v), c1, 0, 0, 0);

        #pragma unroll
        for (int r = 0; r < 12; ++r) qA = fmaf(mwv[r], fmaxf(c0[r], 0.f), qA);
        #pragma unroll
        for (int r = 0; r < 12; ++r) qB = fmaf(mwv[r], fmaxf(c1[r], 0.f), qB);
    }

    // combine lane halves
    float sA = __builtin_bit_cast(float, __builtin_amdgcn_ds_bpermute(srcX, __builtin_bit_cast(int, qA)));
    float sB = __builtin_bit_cast(float, __builtin_amdgcn_ds_bpermute(srcX, __builtin_bit_cast(int, qB)));
    float qv = (lo ? qA + sA : qB + sB) + 7.f * ws[WS_MB];
    if (b < B) out[(size_t)b*8 + p] = qv;
}

extern "C" void kernel_launch(void* const* d_in, const int* in_sizes, int n_in,
                              void* d_out, int out_size, void* d_ws, size_t ws_size,
                              hipStream_t stream) {
    const float* states       = (const float*)d_in[0];
    const int*   p2m          = (const int*)  d_in[1];
    const int*   comp_mask    = (const int*)  d_in[3];
    const float* p_emb        = (const float*)d_in[4];
    const float* d_W          = (const float*)d_in[5];
    const float* d_b          = (const float*)d_in[6];
    const float* lane_W       = (const float*)d_in[7];
    const float* lane_b       = (const float*)d_in[8];
    const float* lane_conv_W  = (const float*)d_in[9];
    const float* lane_conv_b  = (const float*)d_in[10];
    const float* rel_emb      = (const float*)d_in[11];
    const float* rel_conv_W   = (const float*)d_in[12];
    const float* rel_conv_b   = (const float*)d_in[13];
    const float* hid_W        = (const float*)d_in[14];
    const float* hid_b        = (const float*)d_in[15];
    const float* merge_W      = (const float*)d_in[16];
    const float* merge_b      = (const float*)d_in[17];
    float* out = (float*)d_out;
    float* ws  = (float*)d_ws;

    frap_setup<<<1, 256, 0, stream>>>(p2m, comp_mask, p_emb, d_W, d_b, lane_W, lane_b,
        lane_conv_W, lane_conv_b, rel_emb, rel_conv_W, rel_conv_b, hid_W, hid_b,
        merge_W, merge_b, ws);

    int B = in_sizes[0] / 13;
    int grid = (B + 63) / 64;
    frap_main<<<grid, 512, 0, stream>>>(states, comp_mask, ws, out, B);
}